// Round 13
// baseline (3946.408 us; speedup 1.0000x reference)
//
#include <hip/hip_runtime.h>
#include <cstdio>
#include <cstdint>

#define S8     8
#define TENC   12
#define HDIM   256
#define FDIM   316
#define BATCH  1024
#define LDEC   48
#define DBT    16           // batch rows per block in rec_phase; grid 512, 2 blocks/CU
#define KA     264          // hA row stride in shorts (16B-aligned rows)
#define SCALE_ATTN 0.0625f  // 1/sqrt(256)

typedef short bf16x8 __attribute__((ext_vector_type(8)));
typedef float f32x4  __attribute__((ext_vector_type(4)));

__device__ __forceinline__ float sigf(float x) { return 1.0f / (1.0f + expf(-x)); }

__device__ __forceinline__ unsigned short f2bf(float f) {
  unsigned u = __builtin_bit_cast(unsigned, f);
  unsigned r = (u + 0x7fffu + ((u >> 16) & 1u)) >> 16;   // RNE
  return (unsigned short)r;
}
__device__ __forceinline__ float bflo(unsigned u) {
  return __builtin_bit_cast(float, u << 16);
}
__device__ __forceinline__ float bfhi(unsigned u) {
  return __builtin_bit_cast(float, u & 0xffff0000u);
}

#define MFMA(acc, a, b) acc = __builtin_amdgcn_mfma_f32_16x16x32_bf16(a, b, acc, 0, 0, 0)

// DOT8: q = 4 u32 holding 8 bf16 (lo/hi pairs), hp = 8 floats
#define DOT8(a, q, hp) \
  a = fmaf(bflo(q.x), hp[0], a); a = fmaf(bfhi(q.x), hp[1], a); \
  a = fmaf(bflo(q.y), hp[2], a); a = fmaf(bfhi(q.y), hp[3], a); \
  a = fmaf(bflo(q.z), hp[4], a); a = fmaf(bfhi(q.z), hp[5], a); \
  a = fmaf(bflo(q.w), hp[6], a); a = fmaf(bfhi(q.w), hp[7], a);

// UNPS: 4 u32 (= 8 ushorts of a bf16 array) -> 8 floats
#define UNPS(dst, off, q) \
  dst[off+0] = bflo(q.x); dst[off+1] = bfhi(q.x); \
  dst[off+2] = bflo(q.y); dst[off+3] = bfhi(q.y); \
  dst[off+4] = bflo(q.z); dst[off+5] = bfhi(q.z); \
  dst[off+6] = bflo(q.w); dst[off+7] = bfhi(q.w);

// ---------------- transpose: in [S][R][C] -> out [S][C][R] ----------------
__global__ __launch_bounds__(256) void transpose_k(const float* __restrict__ in,
                                                   float* __restrict__ out,
                                                   int R, int C) {
  __shared__ float tile[32][33];
  const int s = blockIdx.z;
  const size_t base = (size_t)s * R * C;
  const int r0 = blockIdx.y * 32, c0 = blockIdx.x * 32;
  const int tx = threadIdx.x & 31, ty = threadIdx.x >> 5;
  for (int i = ty; i < 32; i += 8) {
    int r = r0 + i, c = c0 + tx;
    if (r < R && c < C) tile[i][tx] = in[base + (size_t)r * C + c];
  }
  __syncthreads();
  for (int i = ty; i < 32; i += 8) {
    int c = c0 + i, r = r0 + tx;
    if (c < C && r < R) out[base + (size_t)c * R + r] = tile[tx][i];
  }
}

// ---- fold GEMM: out[s][r][col] = sum_e A[s][e][r] * B[s][e][col], 256x256, K=256 ----
__global__ __launch_bounds__(256) void fold_gemm(const float* __restrict__ A, size_t sA,
                                                 const float* __restrict__ Bm, size_t sB,
                                                 float* __restrict__ out, size_t sO) {
  const int s = blockIdx.y, r0 = blockIdx.x * 32, col = threadIdx.x;
  A += (size_t)s * sA; Bm += (size_t)s * sB; out += (size_t)s * sO;
  float acc[32] = {};
  for (int e = 0; e < HDIM; ++e) {
    const float bvv = Bm[(size_t)e * HDIM + col];
#pragma unroll
    for (int r = 0; r < 32; ++r) acc[r] = fmaf(A[(size_t)e * HDIM + r0 + r], bvv, acc[r]);
  }
  for (int r = 0; r < 32; ++r) out[(size_t)(r0 + r) * HDIM + col] = acc[r];
}

// ---- pack gate weights [S][1024][Ksrc] into B-fragment layout, hi+lo bf16 ----
__global__ __launch_bounds__(64) void pack_hl(const float* __restrict__ src, int Ksrc, int ksT,
                                              bf16x8* __restrict__ outhi,
                                              bf16x8* __restrict__ outlo) {
  const int s = blockIdx.z, ks = blockIdx.y, nt = blockIdx.x;
  const int lane = threadIdx.x, l15 = lane & 15, quad = lane >> 4;
  const int n = nt * 16 + l15, kb = ks * 32 + quad * 8;
  const float* row = src + ((size_t)s * 1024 + n) * Ksrc;
  union { bf16x8 v; unsigned short e[8]; } h, l;
#pragma unroll
  for (int j = 0; j < 8; ++j) {
    const int k = kb + j;
    const float v = (k < Ksrc) ? row[k] : 0.f;
    const unsigned short hi = f2bf(v);
    h.e[j] = hi;
    l.e[j] = f2bf(v - bflo(hi));
  }
  const size_t idx = (((size_t)s * ksT + ks) * 64 + nt) * 64 + lane;
  outhi[idx] = h.v;
  outlo[idx] = l.v;
}

// ---- pack attention fold matrix P [S][256][256] into B-frag (single bf16), nt 0..15 ----
__global__ __launch_bounds__(64) void pack_s(const float* __restrict__ src, int ntOff,
                                             bf16x8* __restrict__ out) {
  const int s = blockIdx.z, ks = blockIdx.y, nt = blockIdx.x;
  const int lane = threadIdx.x, l15 = lane & 15, quad = lane >> 4;
  const int n = nt * 16 + l15, kb = ks * 32 + quad * 8;
  const float* row = src + ((size_t)s * 256 + n) * 256;
  union { bf16x8 v; unsigned short e[8]; } h;
#pragma unroll
  for (int j = 0; j < 8; ++j) h.e[j] = f2bf(row[kb + j]);
  out[(((size_t)s * 8 + ks) * 32 + ntOff + nt) * 64 + lane] = h.v;
}

// ---- fold vectors: kbv = Wk^T bq ; cbias = Wo bv + b_out ----
__global__ __launch_bounds__(256) void fold_vec2(const float* __restrict__ Win,
                                                 const float* __restrict__ bin,
                                                 const float* __restrict__ Wout,
                                                 const float* __restrict__ bout,
                                                 float* __restrict__ kbv,
                                                 float* __restrict__ cbias) {
  const int s = blockIdx.x, t = threadIdx.x;
  const float* bq = bin + s * 768;
  const float* bv = bin + s * 768 + 512;
  float a0 = 0.f, a1 = 0.f;
  for (int e = 0; e < 256; ++e) {
    a0 = fmaf(Win[((size_t)s * 768 + 256 + e) * 256 + t], bq[e], a0);
    a1 = fmaf(Wout[((size_t)s * 256 + t) * 256 + e], bv[e], a1);
  }
  kbv[s * 256 + t] = a0;
  cbias[s * 256 + t] = a1 + bout[s * 256 + t];
}

// ---- mvw[s][k] = sum_o wfo2[s][o] * Mv[s][o][k]  (folds the whole Mv GEMM away) ----
__global__ __launch_bounds__(256) void fold_mvw(const float* __restrict__ Mv,
                                                const float* __restrict__ Wfo,
                                                float* __restrict__ mvw) {
  const int s = blockIdx.x, k = threadIdx.x;
  float a = 0.f;
  for (int o = 0; o < 256; ++o)
    a = fmaf(Wfo[s * 512 + 256 + o], Mv[((size_t)s * 256 + o) * 256 + k], a);
  mvw[s * 256 + k] = a;
}

__global__ void fold_bias(const float* __restrict__ a, const float* __restrict__ b,
                          float* __restrict__ o, int n) {
  int i = blockIdx.x * 256 + threadIdx.x;
  if (i < n) o[i] = a[i] + b[i];
}

__global__ void build_decin(const float* __restrict__ x, const float* __restrict__ tgt,
                            float* __restrict__ dec_in) {
  int idx = blockIdx.x * 256 + threadIdx.x;
  if (idx >= LDEC * BATCH) return;
  int l = idx >> 10, b = idx & 1023;
  dec_in[idx] = (l == 0) ? x[(size_t)b * 96 * FDIM + 95 * FDIM]
                         : tgt[(size_t)b * LDEC + (l - 1)];
}

// =============== PHASE A: the recurrence, and ONLY the recurrence ===============
// R12 post-mortem: at 512 threads the allocator budget is 128 VGPRs (empirical
// law: budget = 65536/block_threads, immovable) and demand ~150 spilled ~900 MB
// of latency-serialized scratch reads into the recurrent loop.
// FIX: 256-thread blocks -> budget 256. 4 waves, DBT=16; wave w owns h-cols
// [64w,64w+64) as 4 col-slices (nt = g*16 + 4w + st). Per-thread state:
// acc[4][4]=64 + biases 48 + cst/hv 32 + frags 16 + temps ~35 = ~195 < 256.
// grid 512, 2 blocks/CU (VGPR-capped); blocks c and c+256 land on CU c and
// share stream s = c&7 -> per-XCD weight pinning preserved, one dispatch round.
__global__ __launch_bounds__(256) void rec_phase(
    const float* __restrict__ x,
    const bf16x8* __restrict__ WxH, const bf16x8* __restrict__ WxL,
    const bf16x8* __restrict__ WeH, const bf16x8* __restrict__ WeL,
    const bf16x8* __restrict__ WdH, const bf16x8* __restrict__ WdL,
    const float* __restrict__ be, const float* __restrict__ bd,
    const float* __restrict__ wihd, const float* __restrict__ Wfo,
    const float* __restrict__ decin,
    unsigned* __restrict__ hEnc,         // [t][s][b][e] packed hi|lo
    unsigned short* __restrict__ hDec,   // [l][s][b][e] bf16 hi
    float* __restrict__ hdPart)          // [l][s][b] = h_dec . wfo1 (fp32)
{
  __shared__ unsigned short hAhi[DBT * KA];   // 8.4 KB
  __shared__ unsigned short hAlo[DBT * KA];   // 8.4 KB
  __shared__ float scrR[DBT * 4];             // 256 B (hd partials)

  const int bid = blockIdx.x;
  const int s = bid & 7, b0 = (bid >> 3) * DBT;
  const int tid = threadIdx.x;
  const int w = tid >> 6, lane = tid & 63, l15 = lane & 15, quad = lane >> 4;

  for (int i = tid; i < DBT * KA; i += 256) { hAhi[i] = 0; hAlo[i] = 0; }

  // per-lane constants: this thread's 4 col-slices J = g*256 + 64w + 16st + l15
  float beV[4][4], bdV[4][4], wdV[4][4], wfoV[4];
#pragma unroll
  for (int g = 0; g < 4; ++g)
#pragma unroll
    for (int st = 0; st < 4; ++st) {
      const int J = g * 256 + 64 * w + 16 * st + l15;
      beV[g][st] = be[s * 1024 + J];
      bdV[g][st] = bd[s * 1024 + J];
      wdV[g][st] = wihd[s * 1024 + J];
    }
#pragma unroll
  for (int st = 0; st < 4; ++st) wfoV[st] = Wfo[s * 512 + 64 * w + 16 * st + l15];

  float cst[4][4];   // [st][reg]
#pragma unroll
  for (int a = 0; a < 4; ++a)
#pragma unroll
    for (int r = 0; r < 4; ++r) cst[a][r] = 0.f;

  const bf16x8* wxh = WxH + (size_t)s * 10 * 64 * 64;
  const bf16x8* wxl = WxL + (size_t)s * 10 * 64 * 64;
  const bf16x8* weh = WeH + (size_t)s * 8 * 64 * 64;
  const bf16x8* wel = WeL + (size_t)s * 8 * 64 * 64;
  const bf16x8* wdh = WdH + (size_t)s * 8 * 64 * 64;
  const bf16x8* wdl = WdL + (size_t)s * 8 * 64 * 64;

  __syncthreads();

  // ===================== encoder =====================
  for (int t = 0; t < TENC; ++t) {
    f32x4 acc[4][4];   // [g][st]
#pragma unroll
    for (int g = 0; g < 4; ++g)
#pragma unroll
      for (int st = 0; st < 4; ++st) acc[g][st] = (f32x4){0.f, 0.f, 0.f, 0.f};

    const size_t xoff = (size_t)(s * TENC + t) * FDIM;
    for (int ks = 0; ks < 10; ++ks) {
      bf16x8 axh, axl;
      {
        const f32x4* xr = (const f32x4*)(x + (size_t)(b0 + l15) * (96 * FDIM)
                                         + xoff + ks * 32 + quad * 8);
        const f32x4 v0 = __builtin_nontemporal_load(xr);
        f32x4 v1;
        if (ks == 9 && quad == 3) v1 = (f32x4){0.f, 0.f, 0.f, 0.f};
        else v1 = __builtin_nontemporal_load(xr + 1);
        float vv[8];
#pragma unroll
        for (int j = 0; j < 4; ++j) { vv[j] = v0[j]; vv[4 + j] = v1[j]; }
        union { bf16x8 v; unsigned short e[8]; } uh, ul;
#pragma unroll
        for (int j = 0; j < 8; ++j) {
          const unsigned short hi = f2bf(vv[j]);
          uh.e[j] = hi;
          ul.e[j] = f2bf(vv[j] - bflo(hi));
        }
        axh = uh.v; axl = ul.v;
      }
#pragma unroll
      for (int g = 0; g < 4; ++g)
#pragma unroll
        for (int st = 0; st < 4; ++st) {
          const int nt = g * 16 + 4 * w + st;
          const bf16x8 bh = wxh[(ks * 64 + nt) * 64 + lane];
          const bf16x8 bl = wxl[(ks * 64 + nt) * 64 + lane];
          MFMA(acc[g][st], axh, bh); MFMA(acc[g][st], axh, bl); MFMA(acc[g][st], axl, bh);
        }
    }
#pragma unroll 2
    for (int ks = 0; ks < 8; ++ks) {
      const int ao = l15 * KA + ks * 32 + quad * 8;
      const bf16x8 ah = *(const bf16x8*)&hAhi[ao];
      const bf16x8 al = *(const bf16x8*)&hAlo[ao];
#pragma unroll
      for (int g = 0; g < 4; ++g)
#pragma unroll
        for (int st = 0; st < 4; ++st) {
          const int nt = g * 16 + 4 * w + st;
          const bf16x8 bh = weh[(ks * 64 + nt) * 64 + lane];
          const bf16x8 bl = wel[(ks * 64 + nt) * 64 + lane];
          MFMA(acc[g][st], ah, bh); MFMA(acc[g][st], ah, bl); MFMA(acc[g][st], al, bh);
        }
    }
    float hv[4][4];   // [st][reg]
#pragma unroll
    for (int st = 0; st < 4; ++st)
#pragma unroll
      for (int reg = 0; reg < 4; ++reg) {
        const float gi = sigf(acc[0][st][reg] + beV[0][st]);
        const float gf = sigf(acc[1][st][reg] + beV[1][st]);
        const float gg = tanhf(acc[2][st][reg] + beV[2][st]);
        const float go = sigf(acc[3][st][reg] + beV[3][st]);
        const float cn = fmaf(gf, cst[st][reg], gi * gg);
        cst[st][reg] = cn;
        hv[st][reg] = go * tanhf(cn);
      }
    __syncthreads();
#pragma unroll
    for (int st = 0; st < 4; ++st)
#pragma unroll
      for (int reg = 0; reg < 4; ++reg) {
        const int R = 4 * quad + reg;
        const int J = 64 * w + 16 * st + l15;
        const float v = hv[st][reg];
        const unsigned short hi = f2bf(v);
        const unsigned short lo = f2bf(v - bflo(hi));
        hAhi[R * KA + J] = hi;
        hAlo[R * KA + J] = lo;
        __builtin_nontemporal_store((unsigned)hi | ((unsigned)lo << 16),
            &hEnc[((size_t)(t * S8 + s) * BATCH + b0 + R) * HDIM + J]);
      }
    __syncthreads();
  }

  // ===================== decoder (LSTM only + fp32 hd dot) =====================
  for (int l = 0; l < LDEC; ++l) {
    f32x4 acc[4][4];
#pragma unroll
    for (int g = 0; g < 4; ++g)
#pragma unroll
      for (int st = 0; st < 4; ++st) acc[g][st] = (f32x4){0.f, 0.f, 0.f, 0.f};

#pragma unroll 2
    for (int ks = 0; ks < 8; ++ks) {
      const int ao = l15 * KA + ks * 32 + quad * 8;
      const bf16x8 ah = *(const bf16x8*)&hAhi[ao];
      const bf16x8 al = *(const bf16x8*)&hAlo[ao];
#pragma unroll
      for (int g = 0; g < 4; ++g)
#pragma unroll
        for (int st = 0; st < 4; ++st) {
          const int nt = g * 16 + 4 * w + st;
          const bf16x8 bh = wdh[(ks * 64 + nt) * 64 + lane];
          const bf16x8 bl = wdl[(ks * 64 + nt) * 64 + lane];
          MFMA(acc[g][st], ah, bh); MFMA(acc[g][st], ah, bl); MFMA(acc[g][st], al, bh);
        }
    }
    float hv[4][4];
    {
      float itv[4];
#pragma unroll
      for (int reg = 0; reg < 4; ++reg)
        itv[reg] = decin[(size_t)l * BATCH + b0 + 4 * quad + reg];
#pragma unroll
      for (int reg = 0; reg < 4; ++reg) {
        const float it = itv[reg];
#pragma unroll
        for (int st = 0; st < 4; ++st) {
          const float gi = sigf(fmaf(it, wdV[0][st], acc[0][st][reg] + bdV[0][st]));
          const float gf = sigf(fmaf(it, wdV[1][st], acc[1][st][reg] + bdV[1][st]));
          const float gg = tanhf(fmaf(it, wdV[2][st], acc[2][st][reg] + bdV[2][st]));
          const float go = sigf(fmaf(it, wdV[3][st], acc[3][st][reg] + bdV[3][st]));
          const float cn = fmaf(gf, cst[st][reg], gi * gg);
          cst[st][reg] = cn;
          hv[st][reg] = go * tanhf(cn);
        }
      }
    }
    __syncthreads();
#pragma unroll
    for (int st = 0; st < 4; ++st)
#pragma unroll
      for (int reg = 0; reg < 4; ++reg) {
        const int R = 4 * quad + reg;
        const int J = 64 * w + 16 * st + l15;
        const float v = hv[st][reg];
        const unsigned short hi = f2bf(v);
        hAhi[R * KA + J] = hi;
        hAlo[R * KA + J] = f2bf(v - bflo(hi));
        __builtin_nontemporal_store(hi,
            &hDec[((size_t)(l * S8 + s) * BATCH + b0 + R) * HDIM + J]);
      }
    {
      float part[4];
#pragma unroll
      for (int reg = 0; reg < 4; ++reg) {
        float a = 0.f;
#pragma unroll
        for (int st = 0; st < 4; ++st) a = fmaf(hv[st][reg], wfoV[st], a);
        part[reg] = a;
      }
#pragma unroll
      for (int i = 0; i < 4; ++i) {
        float v = part[i];
        v += __shfl_xor(v, 1, 16);
        v += __shfl_xor(v, 2, 16);
        v += __shfl_xor(v, 4, 16);
        v += __shfl_xor(v, 8, 16);
        part[i] = v;
      }
      if (l15 == 0) {
#pragma unroll
        for (int reg = 0; reg < 4; ++reg)
          scrR[(4 * quad + reg) * 4 + w] = part[reg];
      }
    }
    __syncthreads();
    if (tid < DBT) {
      float a = 0.f;
#pragma unroll
      for (int p = 0; p < 4; ++p) a += scrR[tid * 4 + p];
      hdPart[((size_t)l * S8 + s) * BATCH + b0 + tid] = a;
    }
    // no extra barrier: scrR's next write is after next iter's first sync
  }
}

// =============== PHASE B: attention + output, fully parallel ===============
// grid (64 chunks, 8 s) x 256 thr. Per block: 16 batch rows.
// Recomputes kp = P . h_enc (MFMA, into LDS), folds kbs/vw via vectors, then
// loops l=0..47 over scores/softmax/out. No recurrence -> latency-irrelevant.
__global__ __launch_bounds__(256) void attn_phase(
    const unsigned* __restrict__ hEnc, const unsigned short* __restrict__ hDec,
    const bf16x8* __restrict__ AMvF,
    const float* __restrict__ kbv, const float* __restrict__ cbias,
    const float* __restrict__ mvw,
    const float* __restrict__ Wfo, const float* __restrict__ bfo,
    const float* __restrict__ hdPart,
    float* __restrict__ douts)
{
  __shared__ unsigned short kpL[TENC][16][KA];  // 101.4 KB
  __shared__ float scr[16 * TENC * 17];         // 13.1 KB (score partials)
  __shared__ float sc[16][TENC];
  __shared__ float kbs[TENC][16];
  __shared__ float vw[TENC][16];

  const int s = blockIdx.y, b0 = blockIdx.x * 16;
  const int tid = threadIdx.x;
  const int w = tid >> 6, lane = tid & 63, l15 = lane & 15, quad = lane >> 4;

  const bf16x8* amv = AMvF + (size_t)s * 8 * 32 * 64;
  const float* kvv = kbv + s * 256;
  const float* mvv = mvw + s * 256;
  const float* cbs = cbias + s * 256;
  const float* wfo = Wfo + s * 512;
  const float bfos = bfo[s];

  float cw = 0.f;
  for (int e = 0; e < 256; ++e) cw = fmaf(cbs[e], wfo[256 + e], cw);

  // --- kp[t] = P . h_enc[t] via MFMA (hi+lo A); rows via l15, nt = 4w+c ---
  for (int t = 0; t < TENC; ++t) {
    f32x4 acc[4];
#pragma unroll
    for (int c = 0; c < 4; ++c) acc[c] = (f32x4){0.f, 0.f, 0.f, 0.f};
    for (int ks = 0; ks < 8; ++ks) {
      const unsigned* hp = hEnc + ((size_t)(t * S8 + s) * BATCH + b0 + l15) * HDIM
                         + ks * 32 + quad * 8;
      union { bf16x8 v; unsigned short e[8]; } uh, ul;
#pragma unroll
      for (int j = 0; j < 8; ++j) {
        const unsigned u = hp[j];
        uh.e[j] = (unsigned short)u;
        ul.e[j] = (unsigned short)(u >> 16);
      }
#pragma unroll
      for (int c = 0; c < 4; ++c) {
        const int nt = w * 4 + c;
        const bf16x8 b = amv[(ks * 32 + nt) * 64 + lane];
        MFMA(acc[c], uh.v, b); MFMA(acc[c], ul.v, b);
      }
    }
#pragma unroll
    for (int c = 0; c < 4; ++c)
#pragma unroll
      for (int reg = 0; reg < 4; ++reg)
        kpL[t][4 * quad + reg][(w * 4 + c) * 16 + l15] = f2bf(acc[c][reg]);
  }
  // --- kbs / vw folds from h_enc (hi+lo floats) ---
  for (int t = 0; t < TENC; ++t) {
    const int row = tid >> 4, p = tid & 15;
    const unsigned* hp = hEnc + ((size_t)(t * S8 + s) * BATCH + b0 + row) * HDIM + p * 16;
    float a = 0.f, b = 0.f;
#pragma unroll
    for (int k = 0; k < 16; ++k) {
      const unsigned u = hp[k];
      const float h = bflo(u) + bfhi(u);
      a = fmaf(kvv[p * 16 + k], h, a);
      b = fmaf(mvv[p * 16 + k], h, b);
    }
    scr[row * 34 + p] = a;
    scr[row * 34 + 17 + p] = b;
    __syncthreads();
    if (tid < 16) {
      float sa = 0.f, sb = 0.f;
#pragma unroll
      for (int p2 = 0; p2 < 16; ++p2) { sa += scr[tid * 34 + p2]; sb += scr[tid * 34 + 17 + p2]; }
      kbs[t][tid] = sa;
      vw[t][tid] = sb;
    }
    __syncthreads();
  }

  // --- per-l scores/softmax/out ---
  for (int l = 0; l < LDEC; ++l) {
    const int row = tid & 15, pp = tid >> 4;  // 16 rows x 16 chunks
    float hh[16];
    {
      const unsigned short* hp = hDec + ((size_t)(l * S8 + s) * BATCH + b0 + row) * HDIM + pp * 16;
      const uint4 q0 = *(const uint4*)hp;
      const uint4 q1 = *(const uint4*)(hp + 8);
      UNPS(hh, 0, q0);
      UNPS(hh, 8, q1);
    }
    // score partials vs kp (bf16, LDS)
#pragma unroll 2
    for (int t = 0; t < TENC; ++t) {
      const uint4 q0 = *(const uint4*)&kpL[t][row][pp * 16];
      const uint4 q1 = *(const uint4*)&kpL[t][row][pp * 16 + 8];
      float a = 0.f;
      { const float* hp8 = &hh[0]; DOT8(a, q0, hp8); }
      { const float* hp8 = &hh[8]; DOT8(a, q1, hp8); }
      scr[(row * TENC + t) * 17 + pp] = a;
    }
    __syncthreads();
    if (tid < 192) {
      const int r2 = tid & 15, t2 = tid >> 4;
      float a = kbs[t2][r2];
#pragma unroll
      for (int p2 = 0; p2 < 16; ++p2) a += scr[(r2 * TENC + t2) * 17 + p2];
      sc[r2][t2] = a * SCALE_ATTN;
    }
    __syncthreads();
    if (tid < 16) {
      float m = sc[tid][0];
#pragma unroll
      for (int t2 = 1; t2 < TENC; ++t2) m = fmaxf(m, sc[tid][t2]);
      float e[TENC], sum = 0.f;
#pragma unroll
      for (int t2 = 0; t2 < TENC; ++t2) { e[t2] = expf(sc[tid][t2] - m); sum += e[t2]; }
      const float inv = 1.0f / sum;
      float av = 0.f;
#pragma unroll
      for (int t2 = 0; t2 < TENC; ++t2) av = fmaf(e[t2] * inv, vw[t2][tid], av);
      const float hd = hdPart[((size_t)l * S8 + s) * BATCH + b0 + tid];
      douts[((size_t)l * S8 + s) * BATCH + b0 + tid] = hd + av + cw + bfos;
    }
    __syncthreads();
  }
}

// ---------------- final fc over streams ----------------
__global__ void final_fc(const float* __restrict__ douts, const float* __restrict__ Wfc,
                         const float* __restrict__ bfc, float* __restrict__ out) {
  int idx = blockIdx.x * 256 + threadIdx.x;
  if (idx >= BATCH * LDEC) return;
  int b = idx / LDEC, l = idx - b * LDEC;
  float a = bfc[0];
#pragma unroll
  for (int s = 0; s < S8; ++s)
    a = fmaf(douts[((size_t)l * S8 + s) * BATCH + b], Wfc[s], a);
  out[idx] = a;
}

extern "C" void kernel_launch(void* const* d_in, const int* in_sizes, int n_in,
                              void* d_out, int out_size, void* d_ws, size_t ws_size,
                              hipStream_t stream) {
  const float* x          = (const float*)d_in[0];
  const float* tgt        = (const float*)d_in[1];
  const float* W_ih_e     = (const float*)d_in[2];
  const float* W_hh_e     = (const float*)d_in[3];
  const float* b_ih_e     = (const float*)d_in[4];
  const float* b_hh_e     = (const float*)d_in[5];
  const float* W_ih_d     = (const float*)d_in[6];
  const float* W_hh_d     = (const float*)d_in[7];
  const float* b_ih_d     = (const float*)d_in[8];
  const float* b_hh_d     = (const float*)d_in[9];
  const float* W_in_attn  = (const float*)d_in[10];
  const float* b_in_attn  = (const float*)d_in[11];
  const float* W_out_attn = (const float*)d_in[12];
  const float* b_out_attn = (const float*)d_in[13];
  const float* W_fcout    = (const float*)d_in[14];
  const float* b_fcout    = (const float*)d_in[15];
  const float* W_fc       = (const float*)d_in[16];
  const float* b_fc       = (const float*)d_in[17];

  char* wsb = (char*)d_ws;
  size_t off = 0;
  auto alloc = [&](size_t bytes) {
    void* p = wsb + off; off += (bytes + 255) & ~(size_t)255; return p;
  };
  float*  douts = (float*)alloc((size_t)LDEC * S8 * BATCH * 4);
  float*  decin = (float*)alloc((size_t)LDEC * BATCH * 4);
  float*  hdPart= (float*)alloc((size_t)LDEC * S8 * BATCH * 4);
  float*  Pmat  = (float*)alloc((size_t)S8 * 256 * 256 * 4);
  float*  Mvmat = (float*)alloc((size_t)S8 * 256 * 256 * 4);
  float*  WoT   = (float*)alloc((size_t)S8 * 256 * 256 * 4);
  bf16x8* WxH   = (bf16x8*)alloc((size_t)S8 * 10 * 64 * 64 * 16);
  bf16x8* WxL   = (bf16x8*)alloc((size_t)S8 * 10 * 64 * 64 * 16);
  bf16x8* WeH   = (bf16x8*)alloc((size_t)S8 * 8 * 64 * 64 * 16);
  bf16x8* WeL   = (bf16x8*)alloc((size_t)S8 * 8 * 64 * 64 * 16);
  bf16x8* WdH   = (bf16x8*)alloc((size_t)S8 * 8 * 64 * 64 * 16);
  bf16x8* WdL   = (bf16x8*)alloc((size_t)S8 * 8 * 64 * 64 * 16);
  bf16x8* AMvF  = (bf16x8*)alloc((size_t)S8 * 8 * 32 * 64 * 16);
  float*  kbv   = (float*)alloc((size_t)S8 * 256 * 4);
  float*  cbias = (float*)alloc((size_t)S8 * 256 * 4);
  float*  mvw   = (float*)alloc((size_t)S8 * 256 * 4);
  float*  beF   = (float*)alloc((size_t)S8 * 1024 * 4);
  float*  bdF   = (float*)alloc((size_t)S8 * 1024 * 4);
  unsigned* hEnc = (unsigned*)alloc((size_t)TENC * S8 * BATCH * HDIM * 4);          // 100.7 MB
  unsigned short* hDec = (unsigned short*)alloc((size_t)LDEC * S8 * BATCH * HDIM * 2); // 201.3 MB
  if (off > ws_size) {
    fprintf(stderr, "kernel_launch: ws too small: need %zu bytes, have %zu\n", off, ws_size);
    return;
  }

  // ---- one-time weight preparation ----
  transpose_k<<<dim3(8, 8, S8), 256, 0, stream>>>(W_out_attn, WoT, 256, 256);
  fold_gemm<<<dim3(8, S8), 256, 0, stream>>>(W_in_attn, (size_t)768 * 256,
                                             W_in_attn + 256 * 256, (size_t)768 * 256,
                                             Pmat, (size_t)256 * 256);
  fold_gemm<<<dim3(8, S8), 256, 0, stream>>>(WoT, (size_t)256 * 256,
                                             W_in_attn + 2 * 256 * 256, (size_t)768 * 256,
                                             Mvmat, (size_t)256 * 256);
  pack_hl<<<dim3(64, 10, S8), 64, 0, stream>>>(W_ih_e, FDIM, 10, WxH, WxL);
  pack_hl<<<dim3(64, 8, S8), 64, 0, stream>>>(W_hh_e, 256, 8, WeH, WeL);
  pack_hl<<<dim3(64, 8, S8), 64, 0, stream>>>(W_hh_d, 256, 8, WdH, WdL);
  pack_s<<<dim3(16, 8, S8), 64, 0, stream>>>(Pmat, 0, AMvF);
  fold_vec2<<<S8, 256, 0, stream>>>(W_in_attn, b_in_attn, W_out_attn, b_out_attn, kbv, cbias);
  fold_mvw<<<S8, 256, 0, stream>>>(Mvmat, W_fcout, mvw);
  fold_bias<<<(S8 * 1024 + 255) / 256, 256, 0, stream>>>(b_ih_e, b_hh_e, beF, S8 * 1024);
  fold_bias<<<(S8 * 1024 + 255) / 256, 256, 0, stream>>>(b_ih_d, b_hh_d, bdF, S8 * 1024);
  build_decin<<<(LDEC * BATCH + 255) / 256, 256, 0, stream>>>(x, tgt, decin);

  // Phase A: the recurrence only (512 blocks x 256 thr, 2 blocks/CU, no spill)
  rec_phase<<<512, 256, 0, stream>>>(
      x, WxH, WxL, WeH, WeL, WdH, WdL, beF, bdF, W_ih_d, W_fcout, decin,
      hEnc, hDec, hdPart);

  // Phase B: attention + outputs (fully parallel over l and batch)
  attn_phase<<<dim3(64, S8), 256, 0, stream>>>(
      hEnc, hDec, AMvF, kbv, cbias, mvw, W_fcout, b_fcout, hdPart, douts);

  final_fc<<<(BATCH * LDEC + 255) / 256, 256, 0, stream>>>(douts, W_fc, b_fc, (float*)d_out);
}

// Round 14
// 2710.423 us; speedup vs baseline: 1.4560x; 1.4560x over previous
//
#include <hip/hip_runtime.h>
#include <cstdio>
#include <cstdint>

#define S8     8
#define TENC   12
#define HDIM   256
#define FDIM   316
#define BATCH  1024
#define LDEC   48
#define DBT    32           // batch rows per block in rec_phase; grid 256 = 1 block/CU
#define KA     264          // hA row stride in shorts (16B-aligned rows)
#define SCALE_ATTN 0.0625f  // 1/sqrt(256)

typedef short bf16x8 __attribute__((ext_vector_type(8)));
typedef float f32x4  __attribute__((ext_vector_type(4)));

__device__ __forceinline__ float sigf(float x) { return 1.0f / (1.0f + expf(-x)); }

__device__ __forceinline__ unsigned short f2bf(float f) {
  unsigned u = __builtin_bit_cast(unsigned, f);
  unsigned r = (u + 0x7fffu + ((u >> 16) & 1u)) >> 16;   // RNE
  return (unsigned short)r;
}
__device__ __forceinline__ float bflo(unsigned u) {
  return __builtin_bit_cast(float, u << 16);
}
__device__ __forceinline__ float bfhi(unsigned u) {
  return __builtin_bit_cast(float, u & 0xffff0000u);
}

#define MFMA(acc, a, b) acc = __builtin_amdgcn_mfma_f32_16x16x32_bf16(a, b, acc, 0, 0, 0)

// DOT8: q = 4 u32 holding 8 bf16 (lo/hi pairs), hp = 8 floats
#define DOT8(a, q, hp) \
  a = fmaf(bflo(q.x), hp[0], a); a = fmaf(bfhi(q.x), hp[1], a); \
  a = fmaf(bflo(q.y), hp[2], a); a = fmaf(bfhi(q.y), hp[3], a); \
  a = fmaf(bflo(q.z), hp[4], a); a = fmaf(bfhi(q.z), hp[5], a); \
  a = fmaf(bflo(q.w), hp[6], a); a = fmaf(bfhi(q.w), hp[7], a);

// UNPS: 4 u32 (= 8 ushorts of a bf16 array) -> 8 floats
#define UNPS(dst, off, q) \
  dst[off+0] = bflo(q.x); dst[off+1] = bfhi(q.x); \
  dst[off+2] = bflo(q.y); dst[off+3] = bfhi(q.y); \
  dst[off+4] = bflo(q.z); dst[off+5] = bfhi(q.z); \
  dst[off+6] = bflo(q.w); dst[off+7] = bfhi(q.w);

// ---------------- transpose: in [S][R][C] -> out [S][C][R] ----------------
__global__ __launch_bounds__(256) void transpose_k(const float* __restrict__ in,
                                                   float* __restrict__ out,
                                                   int R, int C) {
  __shared__ float tile[32][33];
  const int s = blockIdx.z;
  const size_t base = (size_t)s * R * C;
  const int r0 = blockIdx.y * 32, c0 = blockIdx.x * 32;
  const int tx = threadIdx.x & 31, ty = threadIdx.x >> 5;
  for (int i = ty; i < 32; i += 8) {
    int r = r0 + i, c = c0 + tx;
    if (r < R && c < C) tile[i][tx] = in[base + (size_t)r * C + c];
  }
  __syncthreads();
  for (int i = ty; i < 32; i += 8) {
    int c = c0 + i, r = r0 + tx;
    if (c < C && r < R) out[base + (size_t)c * R + r] = tile[tx][i];
  }
}

// ---- fold GEMM: out[s][r][col] = sum_e A[s][e][r] * B[s][e][col], 256x256, K=256 ----
__global__ __launch_bounds__(256) void fold_gemm(const float* __restrict__ A, size_t sA,
                                                 const float* __restrict__ Bm, size_t sB,
                                                 float* __restrict__ out, size_t sO) {
  const int s = blockIdx.y, r0 = blockIdx.x * 32, col = threadIdx.x;
  A += (size_t)s * sA; Bm += (size_t)s * sB; out += (size_t)s * sO;
  float acc[32] = {};
  for (int e = 0; e < HDIM; ++e) {
    const float bvv = Bm[(size_t)e * HDIM + col];
#pragma unroll
    for (int r = 0; r < 32; ++r) acc[r] = fmaf(A[(size_t)e * HDIM + r0 + r], bvv, acc[r]);
  }
  for (int r = 0; r < 32; ++r) out[(size_t)(r0 + r) * HDIM + col] = acc[r];
}

// ---- pack gate weights [S][1024][Ksrc] into B-fragment layout, hi+lo bf16 ----
__global__ __launch_bounds__(64) void pack_hl(const float* __restrict__ src, int Ksrc, int ksT,
                                              bf16x8* __restrict__ outhi,
                                              bf16x8* __restrict__ outlo) {
  const int s = blockIdx.z, ks = blockIdx.y, nt = blockIdx.x;
  const int lane = threadIdx.x, l15 = lane & 15, quad = lane >> 4;
  const int n = nt * 16 + l15, kb = ks * 32 + quad * 8;
  const float* row = src + ((size_t)s * 1024 + n) * Ksrc;
  union { bf16x8 v; unsigned short e[8]; } h, l;
#pragma unroll
  for (int j = 0; j < 8; ++j) {
    const int k = kb + j;
    const float v = (k < Ksrc) ? row[k] : 0.f;
    const unsigned short hi = f2bf(v);
    h.e[j] = hi;
    l.e[j] = f2bf(v - bflo(hi));
  }
  const size_t idx = (((size_t)s * ksT + ks) * 64 + nt) * 64 + lane;
  outhi[idx] = h.v;
  outlo[idx] = l.v;
}

// ---- pack attention fold matrix P [S][256][256] into B-frag (single bf16), nt 0..15 ----
__global__ __launch_bounds__(64) void pack_s(const float* __restrict__ src, int ntOff,
                                             bf16x8* __restrict__ out) {
  const int s = blockIdx.z, ks = blockIdx.y, nt = blockIdx.x;
  const int lane = threadIdx.x, l15 = lane & 15, quad = lane >> 4;
  const int n = nt * 16 + l15, kb = ks * 32 + quad * 8;
  const float* row = src + ((size_t)s * 256 + n) * 256;
  union { bf16x8 v; unsigned short e[8]; } h;
#pragma unroll
  for (int j = 0; j < 8; ++j) h.e[j] = f2bf(row[kb + j]);
  out[(((size_t)s * 8 + ks) * 32 + ntOff + nt) * 64 + lane] = h.v;
}

// ---- fold vectors: kbv = Wk^T bq ; cbias = Wo bv + b_out ----
__global__ __launch_bounds__(256) void fold_vec2(const float* __restrict__ Win,
                                                 const float* __restrict__ bin,
                                                 const float* __restrict__ Wout,
                                                 const float* __restrict__ bout,
                                                 float* __restrict__ kbv,
                                                 float* __restrict__ cbias) {
  const int s = blockIdx.x, t = threadIdx.x;
  const float* bq = bin + s * 768;
  const float* bv = bin + s * 768 + 512;
  float a0 = 0.f, a1 = 0.f;
  for (int e = 0; e < 256; ++e) {
    a0 = fmaf(Win[((size_t)s * 768 + 256 + e) * 256 + t], bq[e], a0);
    a1 = fmaf(Wout[((size_t)s * 256 + t) * 256 + e], bv[e], a1);
  }
  kbv[s * 256 + t] = a0;
  cbias[s * 256 + t] = a1 + bout[s * 256 + t];
}

// ---- mvw[s][k] = sum_o wfo2[s][o] * Mv[s][o][k]  (folds the whole Mv GEMM away) ----
__global__ __launch_bounds__(256) void fold_mvw(const float* __restrict__ Mv,
                                                const float* __restrict__ Wfo,
                                                float* __restrict__ mvw) {
  const int s = blockIdx.x, k = threadIdx.x;
  float a = 0.f;
  for (int o = 0; o < 256; ++o)
    a = fmaf(Wfo[s * 512 + 256 + o], Mv[((size_t)s * 256 + o) * 256 + k], a);
  mvw[s * 256 + k] = a;
}

__global__ void fold_bias(const float* __restrict__ a, const float* __restrict__ b,
                          float* __restrict__ o, int n) {
  int i = blockIdx.x * 256 + threadIdx.x;
  if (i < n) o[i] = a[i] + b[i];
}

__global__ void build_decin(const float* __restrict__ x, const float* __restrict__ tgt,
                            float* __restrict__ dec_in) {
  int idx = blockIdx.x * 256 + threadIdx.x;
  if (idx >= LDEC * BATCH) return;
  int l = idx >> 10, b = idx & 1023;
  dec_in[idx] = (l == 0) ? x[(size_t)b * 96 * FDIM + 95 * FDIM]
                         : tgt[(size_t)b * LDEC + (l - 1)];
}

// =============== PHASE A: the recurrence, and ONLY the recurrence ===============
// Register model (R12+R13 resolved): arch-VGPR cap = 65536/block_threads; MFMA
// accs sit ON TOP in the unified file. 512 thr -> 128 arch + 64 acc = 192/wave
// -> 2 waves/SIMD -> 8 waves/CU (the observed 24%). R12 spilled because arch
// demand ~136 > 128 (biases in regs). R13 proved eliminating spill collapses
// FETCH to the 127 MB design value. THIS version: R12 geometry (DBT=32, 512
// thr, grid 256 = ONE dispatch round, full 8 waves/CU) + biases/wfo moved to
// LDS tables -> arch demand ~110 < 128 -> no spill at full occupancy.
__global__ __launch_bounds__(512) void rec_phase(
    const float* __restrict__ x,
    const bf16x8* __restrict__ WxH, const bf16x8* __restrict__ WxL,
    const bf16x8* __restrict__ WeH, const bf16x8* __restrict__ WeL,
    const bf16x8* __restrict__ WdH, const bf16x8* __restrict__ WdL,
    const float* __restrict__ be, const float* __restrict__ bd,
    const float* __restrict__ wihd, const float* __restrict__ Wfo,
    const float* __restrict__ decin,
    unsigned* __restrict__ hEnc,         // [t][s][b][e] packed hi|lo
    unsigned short* __restrict__ hDec,   // [l][s][b][e] bf16 hi
    float* __restrict__ hdPart)          // [l][s][b] = h_dec . wfo1 (fp32)
{
  __shared__ unsigned short hAhi[DBT * KA];   // 16.9 KB
  __shared__ unsigned short hAlo[DBT * KA];   // 16.9 KB
  __shared__ float beS[1024];                 // 4 KB
  __shared__ float bdS[1024];                 // 4 KB
  __shared__ float wdS[1024];                 // 4 KB
  __shared__ float wfoS[256];                 // 1 KB (wfo1)
  __shared__ float scrR[DBT * 8];             // 1 KB (hd partials)

  const int bid = blockIdx.x;
  const int s = bid & 7, b0 = (bid >> 3) * DBT;
  const int tid = threadIdx.x;
  const int w = tid >> 6, lane = tid & 63, l15 = lane & 15, quad = lane >> 4;

  for (int i = tid; i < DBT * KA; i += 512) { hAhi[i] = 0; hAlo[i] = 0; }
  for (int i = tid; i < 1024; i += 512) {
    beS[i] = be[s * 1024 + i];
    bdS[i] = bd[s * 1024 + i];
    wdS[i] = wihd[s * 1024 + i];
  }
  if (tid < 256) wfoS[tid] = Wfo[s * 512 + tid];

  float cst[2][2][4];
#pragma unroll
  for (int a = 0; a < 2; ++a)
#pragma unroll
    for (int b = 0; b < 2; ++b)
#pragma unroll
      for (int r = 0; r < 4; ++r) cst[a][b][r] = 0.f;

  const bf16x8* wxh = WxH + (size_t)s * 10 * 64 * 64;
  const bf16x8* wxl = WxL + (size_t)s * 10 * 64 * 64;
  const bf16x8* weh = WeH + (size_t)s * 8 * 64 * 64;
  const bf16x8* wel = WeL + (size_t)s * 8 * 64 * 64;
  const bf16x8* wdh = WdH + (size_t)s * 8 * 64 * 64;
  const bf16x8* wdl = WdL + (size_t)s * 8 * 64 * 64;

  __syncthreads();

  // ===================== encoder =====================
  for (int t = 0; t < TENC; ++t) {
    f32x4 acc[2][2][4];
#pragma unroll
    for (int mt = 0; mt < 2; ++mt)
#pragma unroll
      for (int st = 0; st < 2; ++st)
#pragma unroll
        for (int c = 0; c < 4; ++c) acc[mt][st][c] = (f32x4){0.f, 0.f, 0.f, 0.f};

    const size_t xoff = (size_t)(s * TENC + t) * FDIM;
    for (int ks = 0; ks < 10; ++ks) {
      bf16x8 axh[2], axl[2];
#pragma unroll
      for (int mt = 0; mt < 2; ++mt) {
        const f32x4* xr = (const f32x4*)(x + (size_t)(b0 + 16 * mt + l15) * (96 * FDIM)
                                         + xoff + ks * 32 + quad * 8);
        const f32x4 v0 = __builtin_nontemporal_load(xr);
        f32x4 v1;
        if (ks == 9 && quad == 3) v1 = (f32x4){0.f, 0.f, 0.f, 0.f};
        else v1 = __builtin_nontemporal_load(xr + 1);
        float vv[8];
#pragma unroll
        for (int j = 0; j < 4; ++j) { vv[j] = v0[j]; vv[4 + j] = v1[j]; }
        union { bf16x8 v; unsigned short e[8]; } uh, ul;
#pragma unroll
        for (int j = 0; j < 8; ++j) {
          const unsigned short hi = f2bf(vv[j]);
          uh.e[j] = hi;
          ul.e[j] = f2bf(vv[j] - bflo(hi));
        }
        axh[mt] = uh.v; axl[mt] = ul.v;
      }
#pragma unroll
      for (int st = 0; st < 2; ++st)
#pragma unroll
        for (int c = 0; c < 4; ++c) {
          const int nt = c * 16 + 2 * w + st;
          const bf16x8 bh = wxh[(ks * 64 + nt) * 64 + lane];
          const bf16x8 bl = wxl[(ks * 64 + nt) * 64 + lane];
          MFMA(acc[0][st][c], axh[0], bh); MFMA(acc[0][st][c], axh[0], bl); MFMA(acc[0][st][c], axl[0], bh);
          MFMA(acc[1][st][c], axh[1], bh); MFMA(acc[1][st][c], axh[1], bl); MFMA(acc[1][st][c], axl[1], bh);
        }
    }
#pragma unroll 2
    for (int ks = 0; ks < 8; ++ks) {
      bf16x8 ah[2], al[2];
#pragma unroll
      for (int mt = 0; mt < 2; ++mt) {
        const int ao = (16 * mt + l15) * KA + ks * 32 + quad * 8;
        ah[mt] = *(const bf16x8*)&hAhi[ao];
        al[mt] = *(const bf16x8*)&hAlo[ao];
      }
#pragma unroll
      for (int st = 0; st < 2; ++st)
#pragma unroll
        for (int c = 0; c < 4; ++c) {
          const int nt = c * 16 + 2 * w + st;
          const bf16x8 bh = weh[(ks * 64 + nt) * 64 + lane];
          const bf16x8 bl = wel[(ks * 64 + nt) * 64 + lane];
          MFMA(acc[0][st][c], ah[0], bh); MFMA(acc[0][st][c], ah[0], bl); MFMA(acc[0][st][c], al[0], bh);
          MFMA(acc[1][st][c], ah[1], bh); MFMA(acc[1][st][c], ah[1], bl); MFMA(acc[1][st][c], al[1], bh);
        }
    }
    // pointwise LSTM -- gate biases from LDS table
    float hv[2][2][4];
#pragma unroll
    for (int st = 0; st < 2; ++st) {
      const int J0 = 32 * w + 16 * st + l15;
      const float g0 = beS[J0];
      const float g1 = beS[256 + J0];
      const float g2 = beS[512 + J0];
      const float g3 = beS[768 + J0];
#pragma unroll
      for (int mt = 0; mt < 2; ++mt)
#pragma unroll
        for (int reg = 0; reg < 4; ++reg) {
          const float gi = sigf(acc[mt][st][0][reg] + g0);
          const float gf = sigf(acc[mt][st][1][reg] + g1);
          const float gg = tanhf(acc[mt][st][2][reg] + g2);
          const float go = sigf(acc[mt][st][3][reg] + g3);
          const float cn = fmaf(gf, cst[mt][st][reg], gi * gg);
          cst[mt][st][reg] = cn;
          hv[mt][st][reg] = go * tanhf(cn);
        }
    }
    __syncthreads();
#pragma unroll
    for (int mt = 0; mt < 2; ++mt)
#pragma unroll
      for (int st = 0; st < 2; ++st)
#pragma unroll
        for (int reg = 0; reg < 4; ++reg) {
          const int R = 16 * mt + 4 * quad + reg;
          const int J = 32 * w + 16 * st + l15;
          const float v = hv[mt][st][reg];
          const unsigned short hi = f2bf(v);
          const unsigned short lo = f2bf(v - bflo(hi));
          hAhi[R * KA + J] = hi;
          hAlo[R * KA + J] = lo;
          __builtin_nontemporal_store((unsigned)hi | ((unsigned)lo << 16),
              &hEnc[((size_t)(t * S8 + s) * BATCH + b0 + R) * HDIM + J]);
        }
    __syncthreads();
  }

  // ===================== decoder (LSTM only + fp32 hd dot) =====================
  for (int l = 0; l < LDEC; ++l) {
    f32x4 acc[2][2][4];
#pragma unroll
    for (int mt = 0; mt < 2; ++mt)
#pragma unroll
      for (int st = 0; st < 2; ++st)
#pragma unroll
        for (int c = 0; c < 4; ++c) acc[mt][st][c] = (f32x4){0.f, 0.f, 0.f, 0.f};

#pragma unroll 2
    for (int ks = 0; ks < 8; ++ks) {
      bf16x8 ah[2], al[2];
#pragma unroll
      for (int mt = 0; mt < 2; ++mt) {
        const int ao = (16 * mt + l15) * KA + ks * 32 + quad * 8;
        ah[mt] = *(const bf16x8*)&hAhi[ao];
        al[mt] = *(const bf16x8*)&hAlo[ao];
      }
#pragma unroll
      for (int st = 0; st < 2; ++st)
#pragma unroll
        for (int c = 0; c < 4; ++c) {
          const int nt = c * 16 + 2 * w + st;
          const bf16x8 bh = wdh[(ks * 64 + nt) * 64 + lane];
          const bf16x8 bl = wdl[(ks * 64 + nt) * 64 + lane];
          MFMA(acc[0][st][c], ah[0], bh); MFMA(acc[0][st][c], ah[0], bl); MFMA(acc[0][st][c], al[0], bh);
          MFMA(acc[1][st][c], ah[1], bh); MFMA(acc[1][st][c], ah[1], bl); MFMA(acc[1][st][c], al[1], bh);
        }
    }
    // pointwise LSTM -- bd/wd from LDS tables
    float hv[2][2][4];
#pragma unroll
    for (int st = 0; st < 2; ++st) {
      const int J0 = 32 * w + 16 * st + l15;
      const float b0g = bdS[J0];
      const float b1g = bdS[256 + J0];
      const float b2g = bdS[512 + J0];
      const float b3g = bdS[768 + J0];
      const float w0g = wdS[J0];
      const float w1g = wdS[256 + J0];
      const float w2g = wdS[512 + J0];
      const float w3g = wdS[768 + J0];
#pragma unroll
      for (int mt = 0; mt < 2; ++mt)
#pragma unroll
        for (int reg = 0; reg < 4; ++reg) {
          const int R = 16 * mt + 4 * quad + reg;
          const float it = decin[(size_t)l * BATCH + b0 + R];
          const float gi = sigf(fmaf(it, w0g, acc[mt][st][0][reg] + b0g));
          const float gf = sigf(fmaf(it, w1g, acc[mt][st][1][reg] + b1g));
          const float gg = tanhf(fmaf(it, w2g, acc[mt][st][2][reg] + b2g));
          const float go = sigf(fmaf(it, w3g, acc[mt][st][3][reg] + b3g));
          const float cn = fmaf(gf, cst[mt][st][reg], gi * gg);
          cst[mt][st][reg] = cn;
          hv[mt][st][reg] = go * tanhf(cn);
        }
    }
    __syncthreads();
#pragma unroll
    for (int mt = 0; mt < 2; ++mt)
#pragma unroll
      for (int st = 0; st < 2; ++st)
#pragma unroll
        for (int reg = 0; reg < 4; ++reg) {
          const int R = 16 * mt + 4 * quad + reg;
          const int J = 32 * w + 16 * st + l15;
          const float v = hv[mt][st][reg];
          const unsigned short hi = f2bf(v);
          hAhi[R * KA + J] = hi;
          hAlo[R * KA + J] = f2bf(v - bflo(hi));
          __builtin_nontemporal_store(hi,
              &hDec[((size_t)(l * S8 + s) * BATCH + b0 + R) * HDIM + J]);
        }
    // hd = h . wfo1 in fp32 from registers (precision-critical dot)
    {
      float part[8];
#pragma unroll
      for (int mt = 0; mt < 2; ++mt)
#pragma unroll
        for (int reg = 0; reg < 4; ++reg) {
          const int J0 = 32 * w + l15;
          part[mt * 4 + reg] = hv[mt][0][reg] * wfoS[J0] + hv[mt][1][reg] * wfoS[J0 + 16];
        }
#pragma unroll
      for (int i = 0; i < 8; ++i) {
        float v = part[i];
        v += __shfl_xor(v, 1, 16);
        v += __shfl_xor(v, 2, 16);
        v += __shfl_xor(v, 4, 16);
        v += __shfl_xor(v, 8, 16);
        part[i] = v;
      }
      if (l15 == 0) {
#pragma unroll
        for (int mt = 0; mt < 2; ++mt)
#pragma unroll
          for (int reg = 0; reg < 4; ++reg)
            scrR[(16 * mt + 4 * quad + reg) * 8 + w] = part[mt * 4 + reg];
      }
    }
    __syncthreads();
    if (tid < DBT) {
      float a = 0.f;
#pragma unroll
      for (int p = 0; p < 8; ++p) a += scrR[tid * 8 + p];
      hdPart[((size_t)l * S8 + s) * BATCH + b0 + tid] = a;
    }
    // no extra barrier: scrR's next write is after next iter's first sync
  }
}

// =============== PHASE B: attention + output, fully parallel ===============
__global__ __launch_bounds__(256) void attn_phase(
    const unsigned* __restrict__ hEnc, const unsigned short* __restrict__ hDec,
    const bf16x8* __restrict__ AMvF,
    const float* __restrict__ kbv, const float* __restrict__ cbias,
    const float* __restrict__ mvw,
    const float* __restrict__ Wfo, const float* __restrict__ bfo,
    const float* __restrict__ hdPart,
    float* __restrict__ douts)
{
  __shared__ unsigned short kpL[TENC][16][KA];  // 101.4 KB
  __shared__ float scr[16 * TENC * 17];         // 13.1 KB (score partials)
  __shared__ float sc[16][TENC];
  __shared__ float kbs[TENC][16];
  __shared__ float vw[TENC][16];

  const int s = blockIdx.y, b0 = blockIdx.x * 16;
  const int tid = threadIdx.x;
  const int w = tid >> 6, lane = tid & 63, l15 = lane & 15, quad = lane >> 4;

  const bf16x8* amv = AMvF + (size_t)s * 8 * 32 * 64;
  const float* kvv = kbv + s * 256;
  const float* mvv = mvw + s * 256;
  const float* cbs = cbias + s * 256;
  const float* wfo = Wfo + s * 512;
  const float bfos = bfo[s];

  float cw = 0.f;
  for (int e = 0; e < 256; ++e) cw = fmaf(cbs[e], wfo[256 + e], cw);

  // --- kp[t] = P . h_enc[t] via MFMA (hi+lo A); rows via l15, nt = 4w+c ---
  for (int t = 0; t < TENC; ++t) {
    f32x4 acc[4];
#pragma unroll
    for (int c = 0; c < 4; ++c) acc[c] = (f32x4){0.f, 0.f, 0.f, 0.f};
    for (int ks = 0; ks < 8; ++ks) {
      const unsigned* hp = hEnc + ((size_t)(t * S8 + s) * BATCH + b0 + l15) * HDIM
                         + ks * 32 + quad * 8;
      union { bf16x8 v; unsigned short e[8]; } uh, ul;
#pragma unroll
      for (int j = 0; j < 8; ++j) {
        const unsigned u = hp[j];
        uh.e[j] = (unsigned short)u;
        ul.e[j] = (unsigned short)(u >> 16);
      }
#pragma unroll
      for (int c = 0; c < 4; ++c) {
        const int nt = w * 4 + c;
        const bf16x8 b = amv[(ks * 32 + nt) * 64 + lane];
        MFMA(acc[c], uh.v, b); MFMA(acc[c], ul.v, b);
      }
    }
#pragma unroll
    for (int c = 0; c < 4; ++c)
#pragma unroll
      for (int reg = 0; reg < 4; ++reg)
        kpL[t][4 * quad + reg][(w * 4 + c) * 16 + l15] = f2bf(acc[c][reg]);
  }
  // --- kbs / vw folds from h_enc (hi+lo floats) ---
  for (int t = 0; t < TENC; ++t) {
    const int row = tid >> 4, p = tid & 15;
    const unsigned* hp = hEnc + ((size_t)(t * S8 + s) * BATCH + b0 + row) * HDIM + p * 16;
    float a = 0.f, b = 0.f;
#pragma unroll
    for (int k = 0; k < 16; ++k) {
      const unsigned u = hp[k];
      const float h = bflo(u) + bfhi(u);
      a = fmaf(kvv[p * 16 + k], h, a);
      b = fmaf(mvv[p * 16 + k], h, b);
    }
    scr[row * 34 + p] = a;
    scr[row * 34 + 17 + p] = b;
    __syncthreads();
    if (tid < 16) {
      float sa = 0.f, sb = 0.f;
#pragma unroll
      for (int p2 = 0; p2 < 16; ++p2) { sa += scr[tid * 34 + p2]; sb += scr[tid * 34 + 17 + p2]; }
      kbs[t][tid] = sa;
      vw[t][tid] = sb;
    }
    __syncthreads();
  }

  // --- per-l scores/softmax/out ---
  for (int l = 0; l < LDEC; ++l) {
    const int row = tid & 15, pp = tid >> 4;  // 16 rows x 16 chunks
    float hh[16];
    {
      const unsigned short* hp = hDec + ((size_t)(l * S8 + s) * BATCH + b0 + row) * HDIM + pp * 16;
      const uint4 q0 = *(const uint4*)hp;
      const uint4 q1 = *(const uint4*)(hp + 8);
      UNPS(hh, 0, q0);
      UNPS(hh, 8, q1);
    }
    // score partials vs kp (bf16, LDS)
#pragma unroll 2
    for (int t = 0; t < TENC; ++t) {
      const uint4 q0 = *(const uint4*)&kpL[t][row][pp * 16];
      const uint4 q1 = *(const uint4*)&kpL[t][row][pp * 16 + 8];
      float a = 0.f;
      { const float* hp8 = &hh[0]; DOT8(a, q0, hp8); }
      { const float* hp8 = &hh[8]; DOT8(a, q1, hp8); }
      scr[(row * TENC + t) * 17 + pp] = a;
    }
    __syncthreads();
    if (tid < 192) {
      const int r2 = tid & 15, t2 = tid >> 4;
      float a = kbs[t2][r2];
#pragma unroll
      for (int p2 = 0; p2 < 16; ++p2) a += scr[(r2 * TENC + t2) * 17 + p2];
      sc[r2][t2] = a * SCALE_ATTN;
    }
    __syncthreads();
    if (tid < 16) {
      float m = sc[tid][0];
#pragma unroll
      for (int t2 = 1; t2 < TENC; ++t2) m = fmaxf(m, sc[tid][t2]);
      float e[TENC], sum = 0.f;
#pragma unroll
      for (int t2 = 0; t2 < TENC; ++t2) { e[t2] = expf(sc[tid][t2] - m); sum += e[t2]; }
      const float inv = 1.0f / sum;
      float av = 0.f;
#pragma unroll
      for (int t2 = 0; t2 < TENC; ++t2) av = fmaf(e[t2] * inv, vw[t2][tid], av);
      const float hd = hdPart[((size_t)l * S8 + s) * BATCH + b0 + tid];
      douts[((size_t)l * S8 + s) * BATCH + b0 + tid] = hd + av + cw + bfos;
    }
    __syncthreads();
  }
}

// ---------------- final fc over streams ----------------
__global__ void final_fc(const float* __restrict__ douts, const float* __restrict__ Wfc,
                         const float* __restrict__ bfc, float* __restrict__ out) {
  int idx = blockIdx.x * 256 + threadIdx.x;
  if (idx >= BATCH * LDEC) return;
  int b = idx / LDEC, l = idx - b * LDEC;
  float a = bfc[0];
#pragma unroll
  for (int s = 0; s < S8; ++s)
    a = fmaf(douts[((size_t)l * S8 + s) * BATCH + b], Wfc[s], a);
  out[idx] = a;
}

extern "C" void kernel_launch(void* const* d_in, const int* in_sizes, int n_in,
                              void* d_out, int out_size, void* d_ws, size_t ws_size,
                              hipStream_t stream) {
  const float* x          = (const float*)d_in[0];
  const float* tgt        = (const float*)d_in[1];
  const float* W_ih_e     = (const float*)d_in[2];
  const float* W_hh_e     = (const float*)d_in[3];
  const float* b_ih_e     = (const float*)d_in[4];
  const float* b_hh_e     = (const float*)d_in[5];
  const float* W_ih_d     = (const float*)d_in[6];
  const float* W_hh_d     = (const float*)d_in[7];
  const float* b_ih_d     = (const float*)d_in[8];
  const float* b_hh_d     = (const float*)d_in[9];
  const float* W_in_attn  = (const float*)d_in[10];
  const float* b_in_attn  = (const float*)d_in[11];
  const float* W_out_attn = (const float*)d_in[12];
  const float* b_out_attn = (const float*)d_in[13];
  const float* W_fcout    = (const float*)d_in[14];
  const float* b_fcout    = (const float*)d_in[15];
  const float* W_fc       = (const float*)d_in[16];
  const float* b_fc       = (const float*)d_in[17];

  char* wsb = (char*)d_ws;
  size_t off = 0;
  auto alloc = [&](size_t bytes) {
    void* p = wsb + off; off += (bytes + 255) & ~(size_t)255; return p;
  };
  float*  douts = (float*)alloc((size_t)LDEC * S8 * BATCH * 4);
  float*  decin = (float*)alloc((size_t)LDEC * BATCH * 4);
  float*  hdPart= (float*)alloc((size_t)LDEC * S8 * BATCH * 4);
  float*  Pmat  = (float*)alloc((size_t)S8 * 256 * 256 * 4);
  float*  Mvmat = (float*)alloc((size_t)S8 * 256 * 256 * 4);
  float*  WoT   = (float*)alloc((size_t)S8 * 256 * 256 * 4);
  bf16x8* WxH   = (bf16x8*)alloc((size_t)S8 * 10 * 64 * 64 * 16);
  bf16x8* WxL   = (bf16x8*)alloc((size_t)S8 * 10 * 64 * 64 * 16);
  bf16x8* WeH   = (bf16x8*)alloc((size_t)S8 * 8 * 64 * 64 * 16);
  bf16x8* WeL   = (bf16x8*)alloc((size_t)S8 * 8 * 64 * 64 * 16);
  bf16x8* WdH   = (bf16x8*)alloc((size_t)S8 * 8 * 64 * 64 * 16);
  bf16x8* WdL   = (bf16x8*)alloc((size_t)S8 * 8 * 64 * 64 * 16);
  bf16x8* AMvF  = (bf16x8*)alloc((size_t)S8 * 8 * 32 * 64 * 16);
  float*  kbv   = (float*)alloc((size_t)S8 * 256 * 4);
  float*  cbias = (float*)alloc((size_t)S8 * 256 * 4);
  float*  mvw   = (float*)alloc((size_t)S8 * 256 * 4);
  float*  beF   = (float*)alloc((size_t)S8 * 1024 * 4);
  float*  bdF   = (float*)alloc((size_t)S8 * 1024 * 4);
  unsigned* hEnc = (unsigned*)alloc((size_t)TENC * S8 * BATCH * HDIM * 4);          // 100.7 MB
  unsigned short* hDec = (unsigned short*)alloc((size_t)LDEC * S8 * BATCH * HDIM * 2); // 201.3 MB
  if (off > ws_size) {
    fprintf(stderr, "kernel_launch: ws too small: need %zu bytes, have %zu\n", off, ws_size);
    return;
  }

  // ---- one-time weight preparation ----
  transpose_k<<<dim3(8, 8, S8), 256, 0, stream>>>(W_out_attn, WoT, 256, 256);
  fold_gemm<<<dim3(8, S8), 256, 0, stream>>>(W_in_attn, (size_t)768 * 256,
                                             W_in_attn + 256 * 256, (size_t)768 * 256,
                                             Pmat, (size_t)256 * 256);
  fold_gemm<<<dim3(8, S8), 256, 0, stream>>>(WoT, (size_t)256 * 256,
                                             W_in_attn + 2 * 256 * 256, (size_t)768 * 256,
                                             Mvmat, (size_t)256 * 256);
  pack_hl<<<dim3(64, 10, S8), 64, 0, stream>>>(W_ih_e, FDIM, 10, WxH, WxL);
  pack_hl<<<dim3(64, 8, S8), 64, 0, stream>>>(W_hh_e, 256, 8, WeH, WeL);
  pack_hl<<<dim3(64, 8, S8), 64, 0, stream>>>(W_hh_d, 256, 8, WdH, WdL);
  pack_s<<<dim3(16, 8, S8), 64, 0, stream>>>(Pmat, 0, AMvF);
  fold_vec2<<<S8, 256, 0, stream>>>(W_in_attn, b_in_attn, W_out_attn, b_out_attn, kbv, cbias);
  fold_mvw<<<S8, 256, 0, stream>>>(Mvmat, W_fcout, mvw);
  fold_bias<<<(S8 * 1024 + 255) / 256, 256, 0, stream>>>(b_ih_e, b_hh_e, beF, S8 * 1024);
  fold_bias<<<(S8 * 1024 + 255) / 256, 256, 0, stream>>>(b_ih_d, b_hh_d, bdF, S8 * 1024);
  build_decin<<<(LDEC * BATCH + 255) / 256, 256, 0, stream>>>(x, tgt, decin);

  // Phase A: the recurrence only (grid 256, 512 thr, 1 round, no-spill target)
  rec_phase<<<256, 512, 0, stream>>>(
      x, WxH, WxL, WeH, WeL, WdH, WdL, beF, bdF, W_ih_d, W_fcout, decin,
      hEnc, hDec, hdPart);

  // Phase B: attention + outputs (fully parallel over l and batch)
  attn_phase<<<dim3(64, S8), 256, 0, stream>>>(
      hEnc, hDec, AMvF, kbv, cbias, mvw, W_fcout, b_fcout, hdPart, douts);

  final_fc<<<(BATCH * LDEC + 255) / 256, 256, 0, stream>>>(douts, W_fc, b_fc, (float*)d_out);
}